// Round 19
// baseline (145.106 us; speedup 1.0000x reference)
//
#include <hip/hip_runtime.h>
#include <hip/hip_fp16.h>
#include <cstdint>
#include <cstddef>

typedef unsigned short u16;
typedef unsigned int u32;
typedef __attribute__((ext_vector_type(8))) short short8;
typedef __attribute__((ext_vector_type(4))) float f32x4;

static __device__ __forceinline__ u16 f2bf(float x) {
    u32 u = __builtin_bit_cast(u32, x);
    u += 0x7FFFu + ((u >> 16) & 1u);
    return (u16)(u >> 16);
}

// async 16B global->LDS DMA (wave-uniform LDS base + lane*16)
static __device__ __forceinline__ void gload16(const void* g, void* l) {
    __builtin_amdgcn_global_load_lds(
        (const __attribute__((address_space(1))) u32*)g,
        (__attribute__((address_space(3))) u32*)l, 16, 0, 0);
}

// swizzled u16 index of 16B block cb (0..7) in a 64-u16 row
#define SW(row, cb) (((row) * 64) + ((((cb) ^ ((row) & 7))) * 8))

#define C_L2E 0.18033688011112042f  // 0.125 * log2(e): softmax in exp2 domain

// ---------- prep: wqkv/worq transpose + LayerNorm ----------
static __device__ __forceinline__ void wtrans_body(
    const float* __restrict__ src, u16* __restrict__ dst, int R, int C,
    int bx, int by, float t[32][33])
{
    int c0 = bx * 32, r0 = by * 32;
    int tx = threadIdx.x & 31, ty = threadIdx.x >> 5;
    #pragma unroll
    for (int rr = 0; rr < 32; rr += 8)
        t[ty + rr][tx] = src[(size_t)(r0 + ty + rr) * C + c0 + tx];
    __syncthreads();
    #pragma unroll
    for (int rr = 0; rr < 32; rr += 8)
        dst[(size_t)(c0 + ty + rr) * R + r0 + tx] = f2bf(t[tx][ty + rr]);
}

__global__ __launch_bounds__(256) void prep_kernel(
    const float* __restrict__ x, const float* __restrict__ orqy,
    const float* __restrict__ lw, const float* __restrict__ lb,
    const float* __restrict__ w_qkv, const float* __restrict__ w_orq,
    u16* __restrict__ xn, u16* __restrict__ orqn,
    u16* __restrict__ wqkvT, u16* __restrict__ worqT)
{
    __shared__ float t[32][33];
    int id = blockIdx.x;
    if (id < 768) {                       // wtrans w_qkv [512,1536]
        wtrans_body(w_qkv, wqkvT, 512, 1536, id % 48, id / 48, t);
    } else if (id < 1024) {               // wtrans w_orq [512,512]
        int r = id - 768;
        wtrans_body(w_orq, worqT, 512, 512, r & 15, r >> 4, t);
    } else {                              // fused LayerNorm (x rows then ORquery rows)
        int row = (id - 1024) * 4 + (threadIdx.x >> 6); // 0..16383
        const float* src;
        u16* dst;
        if (row < 8192) { src = x + (size_t)row * 512; dst = xn + (size_t)row * 512; }
        else { src = orqy + (size_t)(row - 8192) * 512; dst = orqn + (size_t)(row - 8192) * 512; }
        int lane = threadIdx.x & 63;
        float4 a = *(const float4*)(src + lane * 8);
        float4 b = *(const float4*)(src + lane * 8 + 4);
        float s = a.x + a.y + a.z + a.w + b.x + b.y + b.z + b.w;
        float q = a.x*a.x + a.y*a.y + a.z*a.z + a.w*a.w
                + b.x*b.x + b.y*b.y + b.z*b.z + b.w*b.w;
        #pragma unroll
        for (int off = 32; off >= 1; off >>= 1) {
            s += __shfl_xor(s, off);
            q += __shfl_xor(q, off);
        }
        float mu = s * (1.0f / 512.0f);
        float var = q * (1.0f / 512.0f) - mu * mu;
        float rs = 1.0f / sqrtf(var + 1e-5f);
        float4 w0 = *(const float4*)(lw + lane * 8);
        float4 w1 = *(const float4*)(lw + lane * 8 + 4);
        float4 b0 = *(const float4*)(lb + lane * 8);
        float4 b1 = *(const float4*)(lb + lane * 8 + 4);
        union { u16 h[8]; uint4 v; } ou;
        ou.h[0] = f2bf((a.x - mu) * rs * w0.x + b0.x);
        ou.h[1] = f2bf((a.y - mu) * rs * w0.y + b0.y);
        ou.h[2] = f2bf((a.z - mu) * rs * w0.z + b0.z);
        ou.h[3] = f2bf((a.w - mu) * rs * w0.w + b0.w);
        ou.h[4] = f2bf((b.x - mu) * rs * w1.x + b1.x);
        ou.h[5] = f2bf((b.y - mu) * rs * w1.y + b1.y);
        ou.h[6] = f2bf((b.z - mu) * rs * w1.z + b1.z);
        ou.h[7] = f2bf((b.w - mu) * rs * w1.w + b1.w);
        *(uint4*)(dst + lane * 8) = ou.v;
    }
}

// ---------- bf16 MFMA GEMM (global_load_lds + double-buffer, 1 barrier/step) ----------
// mode 3: grid (16, 80).
//   by 0..15  : AUX blocks (dispatched FIRST) — alpha->ascT transform + woutT.
//   by 16..79 : GEMM, m0=(by-16)*128. bx 0..7 q/k (coalesced epilogue, q*C_L2E);
//               bx 8..11 V^T epilogue; bx 12..15 orq -> oq2.
// mode 2: grid (4, 128): f32 row-major out (A rows = [attout;orattout]).
__global__ __launch_bounds__(256) void gemm_kernel(
    const u16* __restrict__ A_, const u16* __restrict__ Bt_,
    const u16* __restrict__ A2, const u16* __restrict__ Bt2,
    const float* __restrict__ alpha, u16* __restrict__ ascT,
    const float* __restrict__ w_out, u16* __restrict__ woutT,
    int N, int K, int mode,
    u16* __restrict__ oq, u16* __restrict__ ok, u16* __restrict__ ov,
    u16* __restrict__ oq2, float* __restrict__ of)
{
    __shared__ u16 SH[16384];  // As = SH[0:8192], Bs = SH[8192:16384]
    u16* As = SH;
    u16* Bs = SH + 8192;
    int tid = threadIdx.x;

    if (mode == 3 && blockIdx.y < 16) {
        // ---- AUX: alpha transform (32 tiles) + one w_out tile; runs under GEMM ----
        float (*t)[33] = (float(*)[33])SH;   // [32][33] float alias (4224 B)
        int aid = blockIdx.y * 16 + blockIdx.x;   // 0..255
        int tx = tid & 31, ty = tid >> 5;         // 256 thr
        for (int k = 0; k < 32; ++k) {
            int g = aid * 32 + k;                 // 0..8191
            int b = g >> 10, rr_ = g & 1023;
            int i0 = (rr_ >> 5) * 32, j0 = (rr_ & 31) * 32;
            const float* ab = alpha + ((size_t)b << 20);
            u16* atb = ascT + ((size_t)b << 20);
            #pragma unroll
            for (int rr = 0; rr < 32; rr += 8)
                t[ty + rr][tx] = ab[(size_t)(j0 + ty + rr) * 1024 + i0 + tx];
            __syncthreads();
            #pragma unroll
            for (int rr = 0; rr < 32; rr += 8) {
                float v = C_L2E * (1.0f - t[tx][ty + rr]);
                __half hv = __float2half_rn(v);
                atb[(size_t)(i0 + ty + rr) * 1024 + j0 + tx] = __builtin_bit_cast(u16, hv);
            }
            __syncthreads();
        }
        { // woutT tile aid: [512,512] transpose
            int c0 = (aid & 15) * 32, r0 = (aid >> 4) * 32;
            #pragma unroll
            for (int rr = 0; rr < 32; rr += 8)
                t[ty + rr][tx] = w_out[(size_t)(r0 + ty + rr) * 512 + c0 + tx];
            __syncthreads();
            #pragma unroll
            for (int rr = 0; rr < 32; rr += 8)
                woutT[(size_t)(c0 + ty + rr) * 512 + r0 + tx] = f2bf(t[tx][ty + rr]);
        }
        return;
    }

    int bx = blockIdx.x;
    const u16* A = A_;
    const u16* Bt = Bt_;
    bool orqblk = false;
    if (mode == 3 && bx >= 12) { A = A2; Bt = Bt2; orqblk = true; bx -= 12; }
    int m0 = ((mode == 3) ? ((int)blockIdx.y - 16) : (int)blockIdx.y) * 128;
    int n0 = bx * 128;
    int w = tid >> 6, lane = tid & 63;
    int lo = lane & 15, hi = lane >> 4;
    int wm = (w >> 1) * 64, wn = (w & 1) * 64;

    int sr0 = tid >> 2, sr1 = sr0 + 64;
    int sc0 = ((tid & 3) ^ ((sr0 >> 1) & 3)) * 8;
    int sc1 = ((tid & 3) ^ ((sr1 >> 1) & 3)) * 8;
    const u16* aS0 = A + (size_t)(m0 + sr0) * K + sc0;
    const u16* aS1 = A + (size_t)(m0 + sr1) * K + sc1;
    const u16* bS0 = Bt + (size_t)(n0 + sr0) * K + sc0;
    const u16* bS1 = Bt + (size_t)(n0 + sr1) * K + sc1;
    int d0 = w * 512, d1 = 2048 + w * 512; // wave-uniform LDS dest (u16 idx)

    int aoff[4], boff[4];
    #pragma unroll
    for (int f = 0; f < 4; ++f) {
        int ra = wm + f * 16 + lo, rb = wn + f * 16 + lo;
        aoff[f] = ra * 32 + ((hi ^ ((ra >> 1) & 3)) * 8);
        boff[f] = rb * 32 + ((hi ^ ((rb >> 1) & 3)) * 8);
    }

    f32x4 acc[4][4] = {};
    int nk = K >> 5;
    gload16(aS0, &As[d0]);
    gload16(aS1, &As[d1]);
    gload16(bS0, &Bs[d0]);
    gload16(bS1, &Bs[d1]);
    __syncthreads();
    for (int kt = 0; kt < nk; ++kt) {
        int cur = (kt & 1) << 12;
        if (kt + 1 < nk) {
            int ko = (kt + 1) * 32;
            int nxt = ((kt + 1) & 1) << 12;
            gload16(aS0 + ko, &As[nxt + d0]);
            gload16(aS1 + ko, &As[nxt + d1]);
            gload16(bS0 + ko, &Bs[nxt + d0]);
            gload16(bS1 + ko, &Bs[nxt + d1]);
        }
        short8 af[4], bfr[4];
        #pragma unroll
        for (int mf = 0; mf < 4; ++mf) af[mf] = *(const short8*)&As[cur + aoff[mf]];
        #pragma unroll
        for (int nf = 0; nf < 4; ++nf) bfr[nf] = *(const short8*)&Bs[cur + boff[nf]];
        #pragma unroll
        for (int mf = 0; mf < 4; ++mf)
            #pragma unroll
            for (int nf = 0; nf < 4; ++nf)
                acc[mf][nf] = __builtin_amdgcn_mfma_f32_16x16x32_bf16(af[mf], bfr[nf], acc[mf][nf], 0, 0, 0);
        __syncthreads();
    }

    if (mode == 3 && !orqblk && bx >= 8) {
        // ---- V^T epilogue via LDS transpose (coalesced writes) ----
        int bb = m0 >> 10;
        int ibg = m0 & 1023;
        #pragma unroll
        for (int p = 0; p < 2; ++p) {
            if ((w & 1) == p) {
                #pragma unroll
                for (int nf = 0; nf < 4; ++nf) {
                    int d_rel = nf * 16 + lo;
                    int sxi = (d_rel & 7) * 8;
                    #pragma unroll
                    for (int mf = 0; mf < 4; ++mf) {
                        int i_loc = wm + mf * 16 + hi * 4;  // +r, r=0..3
                        u32 lo32 = (u32)f2bf(acc[mf][nf][0]) | ((u32)f2bf(acc[mf][nf][1]) << 16);
                        u32 hi32 = (u32)f2bf(acc[mf][nf][2]) | ((u32)f2bf(acc[mf][nf][3]) << 16);
                        *(u32*)&As[d_rel * 128 + ((i_loc) ^ sxi)] = lo32;
                        *(u32*)&As[d_rel * 128 + ((i_loc + 2) ^ sxi)] = hi32;
                    }
                }
            }
            __syncthreads();
            int d_r0 = tid >> 3;
            int i_b0 = (tid & 7) * 8;
            #pragma unroll
            for (int dd = 0; dd < 64; dd += 32) {
                int d_r = d_r0 + dd;
                int sxi = (d_r & 7) * 8;
                int col = n0 + p * 64 + d_r;
                int h = (col >> 6) & 7;
                int d = col & 63;
                u16* obase = ov + (((size_t)bb * 8 + h) * 64 + d) * 1024 + ibg;
                #pragma unroll
                for (int ii = 0; ii < 128; ii += 64) {
                    uint4 v = *(const uint4*)&As[d_r * 128 + ((i_b0 + ii) ^ sxi)];
                    *(uint4*)&obase[i_b0 + ii] = v;
                }
            }
            __syncthreads();
        }
        return;
    }

    if (mode == 3) {
        // ---- q/k/oq2 epilogue via LDS transpose: [128 i][128 col] bf16 tile ----
        int bb = m0 >> 10;
        int ibg = m0 & 1023;
        bool qscale = (!orqblk && bx < 4);
        u16* og = orqblk ? oq2 : (bx < 4 ? oq : ok);
        int hb = (n0 >> 6) & 7;
        #pragma unroll
        for (int mf = 0; mf < 4; ++mf)
            #pragma unroll
            for (int nf = 0; nf < 4; ++nf)
                #pragma unroll
                for (int r = 0; r < 4; ++r) {
                    int i_loc = wm + mf * 16 + hi * 4 + r;
                    int col = wn + nf * 16 + lo;
                    float val = acc[mf][nf][r];
                    if (qscale) val *= C_L2E;
                    int g = (col >> 3) ^ (i_loc & 15);
                    SH[i_loc * 128 + g * 8 + (col & 7)] = f2bf(val);
                }
        __syncthreads();
        #pragma unroll
        for (int k = 0; k < 8; ++k) {
            int idx = k * 256 + tid;            // 0..2047
            int half = idx >> 10;               // head half (0..1)
            int rem = idx & 1023;
            int row = rem >> 3;                 // i_loc 0..127
            int u8 = rem & 7;                   // 16B granule within 64-col head
            int g = (half * 8 + u8) ^ (row & 15);
            uint4 v = *(const uint4*)&SH[row * 128 + g * 8];
            size_t orow = ((size_t)bb * 8 + hb + half) * 1024 + ibg + row;
            *(uint4*)&og[orow * 64 + u8 * 8] = v;
        }
        return;
    }

    // mode 2: f32 row-major out
    #pragma unroll
    for (int mf = 0; mf < 4; ++mf) {
        #pragma unroll
        for (int nf = 0; nf < 4; ++nf) {
            #pragma unroll
            for (int r = 0; r < 4; ++r) {
                int row = m0 + wm + mf * 16 + hi * 4 + r;
                int col = n0 + wn + nf * 16 + lo;
                of[(size_t)row * N + col] = acc[mf][nf][r];
            }
        }
    }
}

// ---------- fused flash attention: KVBLK=128, 8 barriers (R15 structure) ----------
__global__ __launch_bounds__(512) void attn_fused_kernel(
    const u16* __restrict__ Q, const u16* __restrict__ OQ,
    const u16* __restrict__ Kk, const u16* __restrict__ Vt,
    const u16* __restrict__ asc,
    u16* __restrict__ outS, u16* __restrict__ outO)
{
    __shared__ u16 Kbuf[2][8192];
    __shared__ u16 Vbuf[2][8192];
    __shared__ u16 Ps[8192];

    // XCD swizzle: 512 blocks, each XCD owns one batch (8 bh)
    int id = blockIdx.x;
    int swz = (id & 7) * 64 + (id >> 3);
    int bh = swz >> 3, it = swz & 7;
    int b = bh >> 3, h = bh & 7;
    int i0 = it * 128;
    int tid = threadIdx.x;
    int w = tid >> 6, lane = tid & 63;
    int lo = lane & 15, hi = lane >> 4;

    const u16* Qb = Q + ((size_t)bh * 1024 + i0) * 64;
    const u16* Ob = OQ + ((size_t)bh * 1024 + i0) * 64;
    const u16* Kb = Kk + (size_t)bh * 1024 * 64;
    const u16* Vb = Vt + (size_t)bh * 64 * 1024;

    int sxc = ((lane & 7) ^ (lane >> 3)) * 8;
    int krow0 = w * 16 + (lane >> 3);
    const u16* kS = Kb + (size_t)krow0 * 64 + sxc;
    int vrow = w * 8 + (lane >> 3);
    int sxv = ((lane & 7) ^ (vrow & 7)) * 8;
    const u16* vS = Vb + (size_t)vrow * 1024 + sxv;
    int kd = w * 1024;
    int vd = w * 512;

    const u16* AbL = asc + ((size_t)b << 20) + ((size_t)(i0 + w * 16 + hi * 4) << 10) + lo;

    int qrow = w * 16 + lo;
    short8 qS0 = *(const short8*)&Qb[qrow * 64 + hi * 8];
    short8 qS1 = *(const short8*)&Qb[qrow * 64 + 32 + hi * 8];
    short8 qO0 = *(const short8*)&Ob[qrow * 64 + hi * 8];
    short8 qO1 = *(const short8*)&Ob[qrow * 64 + 32 + hi * 8];

    int jtd = it * 2 + (w >> 2);

    gload16(kS, &Kbuf[0][kd]);
    gload16(kS + 512, &Kbuf[0][kd + 512]);
    gload16(vS, &Vbuf[0][vd]);
    gload16(vS + 64, &Vbuf[0][vd + 4096]);
    __syncthreads();

    f32x4 oS[4] = {}, oO[4] = {};
    float mS[4], lS[4], mO[4], lO[4];
    #pragma unroll
    for (int r = 0; r < 4; ++r) { mS[r] = -1e30f; lS[r] = 0.f; mO[r] = -1e30f; lO[r] = 0.f; }

    for (int jt = 0; jt < 8; ++jt) {
        int j0 = jt * 128;
        int c = jt & 1;

        u16 a_[32];
        #pragma unroll
        for (int sub = 0; sub < 2; ++sub)
            #pragma unroll
            for (int jf = 0; jf < 4; ++jf)
                #pragma unroll
                for (int r = 0; r < 4; ++r)
                    a_[sub * 16 + jf * 4 + r] = AbL[(size_t)(r << 10) + j0 + sub * 64 + jf * 16];

        if (jt < 7) {
            int jn = j0 + 128;
            gload16(kS + (size_t)jn * 64, &Kbuf[c ^ 1][kd]);
            gload16(kS + (size_t)(jn + 8) * 64, &Kbuf[c ^ 1][kd + 512]);
            gload16(vS + jn, &Vbuf[c ^ 1][vd]);
            gload16(vS + jn + 64, &Vbuf[c ^ 1][vd + 4096]);
        }

        #pragma unroll
        for (int sub = 0; sub < 2; ++sub) {
            const u16* Kc = &Kbuf[c][sub * 4096];
            const u16* Vc = &Vbuf[c][sub * 4096];
            const u16* al = &a_[sub * 16];

            // ===== std pass =====
            f32x4 s[4];
            #pragma unroll
            for (int jf = 0; jf < 4; ++jf) {
                short8 kf0 = *(const short8*)&Kc[SW(jf * 16 + lo, hi)];
                short8 kf1 = *(const short8*)&Kc[SW(jf * 16 + lo, 4 + hi)];
                f32x4 z = {};
                z = __builtin_amdgcn_mfma_f32_16x16x32_bf16(qS0, kf0, z, 0, 0, 0);
                z = __builtin_amdgcn_mfma_f32_16x16x32_bf16(qS1, kf1, z, 0, 0, 0);
                s[jf] = z;
            }
            {
                float mx4[4];
                #pragma unroll
                for (int r = 0; r < 4; ++r)
                    mx4[r] = fmaxf(fmaxf(s[0][r], s[1][r]), fmaxf(s[2][r], s[3][r]));
                float need = fmaxf(fmaxf(mx4[0] - mS[0], mx4[1] - mS[1]),
                                   fmaxf(mx4[2] - mS[2], mx4[3] - mS[3]));
                if (!__all(need <= 8.0f)) {
                    #pragma unroll
                    for (int r = 0; r < 4; ++r) {
                        float mx = mx4[r];
                        #pragma unroll
                        for (int msk = 8; msk >= 1; msk >>= 1) mx = fmaxf(mx, __shfl_xor(mx, msk));
                        float mn = fmaxf(mS[r], mx);
                        float scl = __builtin_amdgcn_exp2f(mS[r] - mn);
                        mS[r] = mn;
                        lS[r] *= scl;
                        #pragma unroll
                        for (int df = 0; df < 4; ++df) oS[df][r] *= scl;
                    }
                }
                #pragma unroll
                for (int r = 0; r < 4; ++r)
                    #pragma unroll
                    for (int jf = 0; jf < 4; ++jf) {
                        float p = __builtin_amdgcn_exp2f(s[jf][r] - mS[r]);
                        s[jf][r] = p;
                        lS[r] += p;
                    }
            }
            #pragma unroll
            for (int jf = 0; jf < 4; ++jf)
                #pragma unroll
                for (int r = 0; r < 4; r += 2) {
                    int p0 = hi * 4 + r, p1 = p0 + 1;
                    u32 pk;
                    asm("v_cvt_pk_bf16_f32 %0, %1, %2" : "=v"(pk) : "v"(s[jf][r]), "v"(s[jf][r + 1]));
                    Ps[w * 1024 + p0 * 64 + ((jf * 16 + lo) ^ ((p0 & 7) * 8))] = (u16)pk;
                    Ps[w * 1024 + p1 * 64 + ((jf * 16 + lo) ^ ((p1 & 7) * 8))] = (u16)(pk >> 16);
                }
            {
                short8 pa0 = *(const short8*)&Ps[w * 1024 + SW(lo, hi)];
                short8 pa1 = *(const short8*)&Ps[w * 1024 + SW(lo, 4 + hi)];
                #pragma unroll
                for (int df = 0; df < 4; ++df) {
                    short8 v0 = *(const short8*)&Vc[SW(df * 16 + lo, hi)];
                    short8 v1 = *(const short8*)&Vc[SW(df * 16 + lo, 4 + hi)];
                    oS[df] = __builtin_amdgcn_mfma_f32_16x16x32_bf16(pa0, v0, oS[df], 0, 0, 0);
                    oS[df] = __builtin_amdgcn_mfma_f32_16x16x32_bf16(pa1, v1, oS[df], 0, 0, 0);
                }
            }

            // ===== OR pass =====
            #pragma unroll
            for (int jf = 0; jf < 4; ++jf) {
                short8 kf0 = *(const short8*)&Kc[SW(jf * 16 + lo, hi)];
                short8 kf1 = *(const short8*)&Kc[SW(jf * 16 + lo, 4 + hi)];
                f32x4 z = {};
                z = __builtin_amdgcn_mfma_f32_16x16x32_bf16(qO0, kf0, z, 0, 0, 0);
                z = __builtin_amdgcn_mfma_f32_16x16x32_bf16(qO1, kf1, z, 0, 0, 0);
                s[jf] = z;
            }
            #pragma unroll
            for (int jf = 0; jf < 4; ++jf)
                #pragma unroll
                for (int r = 0; r < 4; ++r) {
                    __half hv = __builtin_bit_cast(__half, al[jf * 4 + r]);
                    s[jf][r] *= __half2float(hv);
                }
            if (jt * 2 + sub == jtd) {
                #pragma unroll
                for (int jf = 0; jf < 4; ++jf)
                    #pragma unroll
                    for (int r = 0; r < 4; ++r)
                        s[jf][r] = ((jf == (w & 3)) && (hi * 4 + r == lo)) ? 0.0f : s[jf][r];
            }
            {
                float mx4[4];
                #pragma unroll
                for (int r = 0; r < 4; ++r)
                    mx4[r] = fmaxf(fmaxf(s[0][r], s[1][r]), fmaxf(s[2][r], s[3][r]));
                float need = fmaxf(fmaxf(mx4[0] - mO[0], mx4[1] - mO[1]),
                                   fmaxf(mx4[2] - mO[2], mx4[3] - mO[3]));
                if (!__all(need <= 8.0f)) {
                    #pragma unroll
                    for (int r = 0; r < 4; ++r) {
                        float mx = mx4[r];
                        #pragma unroll
                        for (int msk = 8; msk >= 1; msk >>= 1) mx = fmaxf(mx, __shfl_xor(mx, msk));
                        float mn = fmaxf(mO[r], mx);
                        float scl = __builtin_amdgcn_exp2f(mO[r] - mn);
                        mO[r] = mn;
                        lO[r] *= scl;
                        #pragma unroll
                        for (int df = 0; df < 4; ++df) oO[df][r] *= scl;
                    }
                }
                #pragma unroll
                for (int r = 0; r < 4; ++r)
                    #pragma unroll
                    for (int jf = 0; jf < 4; ++jf) {
                        float p = __builtin_amdgcn_exp2f(s[jf][r] - mO[r]);
                        s[jf][r] = p;
                        lO[r] += p;
                    }
            }
            #pragma unroll
            for (int jf = 0; jf < 4; ++jf)
                #pragma unroll
                for (int r = 0; r < 4; r += 2) {
                    int p0 = hi * 4 + r, p1 = p0 + 1;
                    u32 pk;
                    asm("v_cvt_pk_bf16_f32 %0, %1, %2" : "=v"(pk) : "v"(s[jf][r]), "v"(s[jf][r + 1]));
                    Ps[w * 1024 + p0 * 64 + ((jf * 16 + lo) ^ ((p0 & 7) * 8))] = (u16)pk;
                    Ps[w * 1024 + p1 * 64 + ((jf * 16 + lo) ^ ((p1 & 7) * 8))] = (u16)(pk >> 16);
                }
            {
                short8 pa0 = *(const short8*)&Ps[w * 1024 + SW(lo, hi)];
                short8 pa1 = *(const short8*)&Ps[w * 1024 + SW(lo, 4 + hi)];
                #pragma unroll
                for (int df = 0; df < 4; ++df) {
                    short8 v0 = *(const short8*)&Vc[SW(df * 16 + lo, hi)];
                    short8 v1 = *(const short8*)&Vc[SW(df * 16 + lo, 4 + hi)];
                    oO[df] = __builtin_amdgcn_mfma_f32_16x16x32_bf16(pa0, v0, oO[df], 0, 0, 0);
                    oO[df] = __builtin_amdgcn_mfma_f32_16x16x32_bf16(pa1, v1, oO[df], 0, 0, 0);
                }
            }
        }

        __syncthreads();
    }

    #pragma unroll
    for (int r = 0; r < 4; ++r) {
        float a = lS[r], c2 = lO[r];
        #pragma unroll
        for (int msk = 8; msk >= 1; msk >>= 1) {
            a += __shfl_xor(a, msk);
            c2 += __shfl_xor(c2, msk);
        }
        lS[r] = 1.0f / a;
        lO[r] = 1.0f / c2;
    }
    size_t obase = ((size_t)b * 1024 + i0 + w * 16 + hi * 4) * 512 + h * 64 + lo;
    #pragma unroll
    for (int df = 0; df < 4; ++df)
        #pragma unroll
        for (int r = 0; r < 4; ++r) {
            outS[obase + (size_t)r * 512 + df * 16] = f2bf(oS[df][r] * lS[r]);
            outO[obase + (size_t)r * 512 + df * 16] = f2bf(oO[df][r] * lO[r]);
        }
}

extern "C" void kernel_launch(void* const* d_in, const int* in_sizes, int n_in,
                              void* d_out, int out_size, void* d_ws, size_t ws_size,
                              hipStream_t stream)
{
    const float* x     = (const float*)d_in[0];
    const float* orqy  = (const float*)d_in[1];
    const float* alpha = (const float*)d_in[2];
    const float* ln_w  = (const float*)d_in[3];
    const float* ln_b  = (const float*)d_in[4];
    const float* w_qkv = (const float*)d_in[5];
    const float* w_orq = (const float*)d_in[6];
    const float* w_out = (const float*)d_in[7];
    float* outp = (float*)d_out;

    char* base = (char*)d_ws;
    size_t off = 0;
    auto alloc = [&](size_t bytes) -> char* {
        char* r = base + off;
        off += (bytes + 255) & ~(size_t)255;
        return r;
    };
    const size_t RC = 8192ull * 512 * 2; // one [8192,512] bf16 buffer
    u16* xn       = (u16*)alloc(RC);
    u16* orqn     = (u16*)alloc(RC);
    u16* qb       = (u16*)alloc(RC);
    u16* kb       = (u16*)alloc(RC);
    u16* vb       = (u16*)alloc(RC);   // stored transposed [bh][64][1024]
    u16* orqb     = (u16*)alloc(RC);
    u16* attout   = (u16*)alloc(RC);   // NOTE: attout/orattout contiguous
    u16* orattout = (u16*)alloc(RC);
    u16* wqkvT    = (u16*)alloc(1536ull * 512 * 2);
    u16* worqT    = (u16*)alloc(512ull * 512 * 2);
    u16* woutT    = (u16*)alloc(512ull * 512 * 2);
    u16* ascT     = (u16*)alloc(8ull * 1024 * 1024 * 2); // fp16 C_L2E*(1-alpha^T)

    // 1) LN + wqkv/worq transpose only
    prep_kernel<<<5120, 256, 0, stream>>>(x, orqy, ln_w, ln_b, w_qkv, w_orq,
                                          xn, orqn, wqkvT, worqT);
    // 2) qkv + orq projections; AUX blocks (alpha transform + woutT) dispatched first
    gemm_kernel<<<dim3(16, 80), 256, 0, stream>>>(xn, wqkvT, orqn, worqT,
                                                  alpha, ascT, w_out, woutT,
                                                  1536, 512, 3,
                                                  qb, kb, vb, orqb, nullptr);
    // 3) fused dual attention
    attn_fused_kernel<<<dim3(512), 512, 0, stream>>>(qb, orqb, kb, vb, ascT, attout, orattout);
    // 4) merged out-projection: A = [attout ; orattout] = 16384 rows (contiguous)
    gemm_kernel<<<dim3(4, 128), 256, 0, stream>>>(attout, woutT, nullptr, nullptr,
                                                  nullptr, nullptr, nullptr, nullptr,
                                                  512, 512, 2,
                                                  nullptr, nullptr, nullptr, nullptr, outp);
}

// Round 20
// 144.466 us; speedup vs baseline: 1.0044x; 1.0044x over previous
//
#include <hip/hip_runtime.h>
#include <hip/hip_fp16.h>
#include <cstdint>
#include <cstddef>

typedef unsigned short u16;
typedef unsigned int u32;
typedef __attribute__((ext_vector_type(8))) short short8;
typedef __attribute__((ext_vector_type(4))) float f32x4;

static __device__ __forceinline__ u16 f2bf(float x) {
    u32 u = __builtin_bit_cast(u32, x);
    u += 0x7FFFu + ((u >> 16) & 1u);
    return (u16)(u >> 16);
}

// async 16B global->LDS DMA (wave-uniform LDS base + lane*16)
static __device__ __forceinline__ void gload16(const void* g, void* l) {
    __builtin_amdgcn_global_load_lds(
        (const __attribute__((address_space(1))) u32*)g,
        (__attribute__((address_space(3))) u32*)l, 16, 0, 0);
}

// swizzled u16 index of 16B block cb (0..7) in a 64-u16 row
#define SW(row, cb) (((row) * 64) + ((((cb) ^ ((row) & 7))) * 8))

#define C_L2E 0.18033688011112042f  // 0.125 * log2(e): softmax in exp2 domain

// ---------- merged preprocessing: 3x weight transpose + alpha transform + LN ----------
static __device__ __forceinline__ void wtrans_body(
    const float* __restrict__ src, u16* __restrict__ dst, int R, int C,
    int bx, int by, float t[32][33])
{
    int c0 = bx * 32, r0 = by * 32;
    int tx = threadIdx.x & 31, ty = threadIdx.x >> 5;
    #pragma unroll
    for (int rr = 0; rr < 32; rr += 8)
        t[ty + rr][tx] = src[(size_t)(r0 + ty + rr) * C + c0 + tx];
    __syncthreads();
    #pragma unroll
    for (int rr = 0; rr < 32; rr += 8)
        dst[(size_t)(c0 + ty + rr) * R + r0 + tx] = f2bf(t[tx][ty + rr]);
}

__global__ __launch_bounds__(256) void prep_kernel(
    const float* __restrict__ x, const float* __restrict__ orqy,
    const float* __restrict__ alpha,
    const float* __restrict__ lw, const float* __restrict__ lb,
    const float* __restrict__ w_qkv, const float* __restrict__ w_orq,
    const float* __restrict__ w_out,
    u16* __restrict__ xn, u16* __restrict__ orqn,
    u16* __restrict__ wqkvT, u16* __restrict__ worqT, u16* __restrict__ woutT,
    u16* __restrict__ ascT)
{
    __shared__ float t[32][33];
    int id = blockIdx.x;
    if (id < 768) {                       // wtrans w_qkv [512,1536]
        wtrans_body(w_qkv, wqkvT, 512, 1536, id % 48, id / 48, t);
    } else if (id < 1024) {               // wtrans w_orq [512,512]
        int r = id - 768;
        wtrans_body(w_orq, worqT, 512, 512, r & 15, r >> 4, t);
    } else if (id < 1280) {               // wtrans w_out [512,512]
        int r = id - 1024;
        wtrans_body(w_out, woutT, 512, 512, r & 15, r >> 4, t);
    } else if (id < 9472) {               // atrans: asc[b][i][j]=fp16(C_L2E*(1-a[b][j][i]))
        int r = id - 1280;
        int bx = r & 31, by = (r >> 5) & 31, b = r >> 10;
        int i0 = by * 32, j0 = bx * 32;
        int tx = threadIdx.x & 31, ty = threadIdx.x >> 5;
        const float* ab = alpha + ((size_t)b << 20);
        u16* atb = ascT + ((size_t)b << 20);
        #pragma unroll
        for (int rr = 0; rr < 32; rr += 8)
            t[ty + rr][tx] = ab[(size_t)(j0 + ty + rr) * 1024 + i0 + tx];
        __syncthreads();
        #pragma unroll
        for (int rr = 0; rr < 32; rr += 8) {
            float v = C_L2E * (1.0f - t[tx][ty + rr]);
            __half hv = __float2half_rn(v);
            atb[(size_t)(i0 + ty + rr) * 1024 + j0 + tx] = __builtin_bit_cast(u16, hv);
        }
    } else {                              // fused LayerNorm (x rows then ORquery rows)
        int row = (id - 9472) * 4 + (threadIdx.x >> 6); // 0..16383
        const float* src;
        u16* dst;
        if (row < 8192) { src = x + (size_t)row * 512; dst = xn + (size_t)row * 512; }
        else { src = orqy + (size_t)(row - 8192) * 512; dst = orqn + (size_t)(row - 8192) * 512; }
        int lane = threadIdx.x & 63;
        float4 a = *(const float4*)(src + lane * 8);
        float4 b = *(const float4*)(src + lane * 8 + 4);
        float s = a.x + a.y + a.z + a.w + b.x + b.y + b.z + b.w;
        float q = a.x*a.x + a.y*a.y + a.z*a.z + a.w*a.w
                + b.x*b.x + b.y*b.y + b.z*b.z + b.w*b.w;
        #pragma unroll
        for (int off = 32; off >= 1; off >>= 1) {
            s += __shfl_xor(s, off);
            q += __shfl_xor(q, off);
        }
        float mu = s * (1.0f / 512.0f);
        float var = q * (1.0f / 512.0f) - mu * mu;
        float rs = 1.0f / sqrtf(var + 1e-5f);
        float4 w0 = *(const float4*)(lw + lane * 8);
        float4 w1 = *(const float4*)(lw + lane * 8 + 4);
        float4 b0 = *(const float4*)(lb + lane * 8);
        float4 b1 = *(const float4*)(lb + lane * 8 + 4);
        union { u16 h[8]; uint4 v; } ou;
        ou.h[0] = f2bf((a.x - mu) * rs * w0.x + b0.x);
        ou.h[1] = f2bf((a.y - mu) * rs * w0.y + b0.y);
        ou.h[2] = f2bf((a.z - mu) * rs * w0.z + b0.z);
        ou.h[3] = f2bf((a.w - mu) * rs * w0.w + b0.w);
        ou.h[4] = f2bf((b.x - mu) * rs * w1.x + b1.x);
        ou.h[5] = f2bf((b.y - mu) * rs * w1.y + b1.y);
        ou.h[6] = f2bf((b.z - mu) * rs * w1.z + b1.z);
        ou.h[7] = f2bf((b.w - mu) * rs * w1.w + b1.w);
        *(uint4*)(dst + lane * 8) = ou.v;
    }
}

// ---------- bf16 MFMA GEMM (global_load_lds + double-buffer, 1 barrier/step) ----------
// mode 3: block-diagonal merged dispatch.
//   bx 0..7  (q/k): coalesced [i][d] epilogue via LDS transpose (q scaled C_L2E)
//   bx 8..11 (V):   coalesced V^T [d][i] epilogue via LDS transpose
//   bx 12..15 (orq): coalesced [i][d] epilogue -> oq2
// mode 2: f32 row-major out (out-projection; A rows = [attout;orattout]).
__global__ __launch_bounds__(256) void gemm_kernel(
    const u16* __restrict__ A_, const u16* __restrict__ Bt_,
    const u16* __restrict__ A2, const u16* __restrict__ Bt2,
    int N, int K, int mode,
    u16* __restrict__ oq, u16* __restrict__ ok, u16* __restrict__ ov,
    u16* __restrict__ oq2, float* __restrict__ of)
{
    __shared__ u16 SH[16384];  // As = SH[0:8192], Bs = SH[8192:16384]
    u16* As = SH;
    u16* Bs = SH + 8192;
    int bx = blockIdx.x;
    const u16* A = A_;
    const u16* Bt = Bt_;
    bool orqblk = false;
    if (mode == 3 && bx >= 12) { A = A2; Bt = Bt2; orqblk = true; bx -= 12; }
    int m0 = blockIdx.y * 128, n0 = bx * 128;
    int tid = threadIdx.x;
    int w = tid >> 6, lane = tid & 63;
    int lo = lane & 15, hi = lane >> 4;
    int wm = (w >> 1) * 64, wn = (w & 1) * 64;

    int sr0 = tid >> 2, sr1 = sr0 + 64;
    int sc0 = ((tid & 3) ^ ((sr0 >> 1) & 3)) * 8;
    int sc1 = ((tid & 3) ^ ((sr1 >> 1) & 3)) * 8;
    const u16* aS0 = A + (size_t)(m0 + sr0) * K + sc0;
    const u16* aS1 = A + (size_t)(m0 + sr1) * K + sc1;
    const u16* bS0 = Bt + (size_t)(n0 + sr0) * K + sc0;
    const u16* bS1 = Bt + (size_t)(n0 + sr1) * K + sc1;
    int d0 = w * 512, d1 = 2048 + w * 512; // wave-uniform LDS dest (u16 idx)

    int aoff[4], boff[4];
    #pragma unroll
    for (int f = 0; f < 4; ++f) {
        int ra = wm + f * 16 + lo, rb = wn + f * 16 + lo;
        aoff[f] = ra * 32 + ((hi ^ ((ra >> 1) & 3)) * 8);
        boff[f] = rb * 32 + ((hi ^ ((rb >> 1) & 3)) * 8);
    }

    f32x4 acc[4][4] = {};
    int nk = K >> 5;
    gload16(aS0, &As[d0]);
    gload16(aS1, &As[d1]);
    gload16(bS0, &Bs[d0]);
    gload16(bS1, &Bs[d1]);
    __syncthreads();
    for (int kt = 0; kt < nk; ++kt) {
        int cur = (kt & 1) << 12;
        if (kt + 1 < nk) {
            int ko = (kt + 1) * 32;
            int nxt = ((kt + 1) & 1) << 12;
            gload16(aS0 + ko, &As[nxt + d0]);
            gload16(aS1 + ko, &As[nxt + d1]);
            gload16(bS0 + ko, &Bs[nxt + d0]);
            gload16(bS1 + ko, &Bs[nxt + d1]);
        }
        short8 af[4], bfr[4];
        #pragma unroll
        for (int mf = 0; mf < 4; ++mf) af[mf] = *(const short8*)&As[cur + aoff[mf]];
        #pragma unroll
        for (int nf = 0; nf < 4; ++nf) bfr[nf] = *(const short8*)&Bs[cur + boff[nf]];
        #pragma unroll
        for (int mf = 0; mf < 4; ++mf)
            #pragma unroll
            for (int nf = 0; nf < 4; ++nf)
                acc[mf][nf] = __builtin_amdgcn_mfma_f32_16x16x32_bf16(af[mf], bfr[nf], acc[mf][nf], 0, 0, 0);
        __syncthreads();
    }

    if (mode == 3 && !orqblk && bx >= 8) {
        // ---- V^T epilogue via LDS transpose (coalesced writes) ----
        int bb = m0 >> 10;
        int ibg = m0 & 1023;
        #pragma unroll
        for (int p = 0; p < 2; ++p) {
            if ((w & 1) == p) {
                #pragma unroll
                for (int nf = 0; nf < 4; ++nf) {
                    int d_rel = nf * 16 + lo;
                    int sxi = (d_rel & 7) * 8;
                    #pragma unroll
                    for (int mf = 0; mf < 4; ++mf) {
                        int i_loc = wm + mf * 16 + hi * 4;  // +r, r=0..3
                        u32 lo32 = (u32)f2bf(acc[mf][nf][0]) | ((u32)f2bf(acc[mf][nf][1]) << 16);
                        u32 hi32 = (u32)f2bf(acc[mf][nf][2]) | ((u32)f2bf(acc[mf][nf][3]) << 16);
                        *(u32*)&As[d_rel * 128 + ((i_loc) ^ sxi)] = lo32;
                        *(u32*)&As[d_rel * 128 + ((i_loc + 2) ^ sxi)] = hi32;
                    }
                }
            }
            __syncthreads();
            int d_r0 = tid >> 3;
            int i_b0 = (tid & 7) * 8;
            #pragma unroll
            for (int dd = 0; dd < 64; dd += 32) {
                int d_r = d_r0 + dd;
                int sxi = (d_r & 7) * 8;
                int col = n0 + p * 64 + d_r;
                int h = (col >> 6) & 7;
                int d = col & 63;
                u16* obase = ov + (((size_t)bb * 8 + h) * 64 + d) * 1024 + ibg;
                #pragma unroll
                for (int ii = 0; ii < 128; ii += 64) {
                    uint4 v = *(const uint4*)&As[d_r * 128 + ((i_b0 + ii) ^ sxi)];
                    *(uint4*)&obase[i_b0 + ii] = v;
                }
            }
            __syncthreads();
        }
        return;
    }

    if (mode == 3) {
        // ---- q/k/oq2 epilogue via LDS transpose: [128 i][128 col] bf16 tile ----
        int bb = m0 >> 10;
        int ibg = m0 & 1023;
        bool qscale = (!orqblk && bx < 4);
        u16* og = orqblk ? oq2 : (bx < 4 ? oq : ok);
        int hb = (n0 >> 6) & 7;
        #pragma unroll
        for (int mf = 0; mf < 4; ++mf)
            #pragma unroll
            for (int nf = 0; nf < 4; ++nf)
                #pragma unroll
                for (int r = 0; r < 4; ++r) {
                    int i_loc = wm + mf * 16 + hi * 4 + r;
                    int col = wn + nf * 16 + lo;
                    float val = acc[mf][nf][r];
                    if (qscale) val *= C_L2E;
                    int g = (col >> 3) ^ (i_loc & 15);
                    SH[i_loc * 128 + g * 8 + (col & 7)] = f2bf(val);
                }
        __syncthreads();
        #pragma unroll
        for (int k = 0; k < 8; ++k) {
            int idx = k * 256 + tid;            // 0..2047
            int half = idx >> 10;               // head half (0..1)
            int rem = idx & 1023;
            int row = rem >> 3;                 // i_loc 0..127
            int u8 = rem & 7;                   // 16B granule within 64-col head
            int g = (half * 8 + u8) ^ (row & 15);
            uint4 v = *(const uint4*)&SH[row * 128 + g * 8];
            size_t orow = ((size_t)bb * 8 + hb + half) * 1024 + ibg + row;
            *(uint4*)&og[orow * 64 + u8 * 8] = v;
        }
        return;
    }

    // mode 2: f32 row-major out
    #pragma unroll
    for (int mf = 0; mf < 4; ++mf) {
        #pragma unroll
        for (int nf = 0; nf < 4; ++nf) {
            #pragma unroll
            for (int r = 0; r < 4; ++r) {
                int row = m0 + wm + mf * 16 + hi * 4 + r;
                int col = n0 + wn + nf * 16 + lo;
                of[(size_t)row * N + col] = acc[mf][nf][r];
            }
        }
    }
}

// ---------- fused flash attention: KVBLK=128, 8 barriers (R15 structure) ----------
__global__ __launch_bounds__(512) void attn_fused_kernel(
    const u16* __restrict__ Q, const u16* __restrict__ OQ,
    const u16* __restrict__ Kk, const u16* __restrict__ Vt,
    const u16* __restrict__ asc,
    u16* __restrict__ outS, u16* __restrict__ outO)
{
    __shared__ u16 Kbuf[2][8192];
    __shared__ u16 Vbuf[2][8192];
    __shared__ u16 Ps[8192];

    // XCD swizzle: 512 blocks, each XCD owns one batch (8 bh)
    int id = blockIdx.x;
    int swz = (id & 7) * 64 + (id >> 3);
    int bh = swz >> 3, it = swz & 7;
    int b = bh >> 3, h = bh & 7;
    int i0 = it * 128;
    int tid = threadIdx.x;
    int w = tid >> 6, lane = tid & 63;
    int lo = lane & 15, hi = lane >> 4;

    const u16* Qb = Q + ((size_t)bh * 1024 + i0) * 64;
    const u16* Ob = OQ + ((size_t)bh * 1024 + i0) * 64;
    const u16* Kb = Kk + (size_t)bh * 1024 * 64;
    const u16* Vb = Vt + (size_t)bh * 64 * 1024;

    int sxc = ((lane & 7) ^ (lane >> 3)) * 8;
    int krow0 = w * 16 + (lane >> 3);
    const u16* kS = Kb + (size_t)krow0 * 64 + sxc;
    int vrow = w * 8 + (lane >> 3);
    int sxv = ((lane & 7) ^ (vrow & 7)) * 8;
    const u16* vS = Vb + (size_t)vrow * 1024 + sxv;
    int kd = w * 1024;
    int vd = w * 512;

    const u16* AbL = asc + ((size_t)b << 20) + ((size_t)(i0 + w * 16 + hi * 4) << 10) + lo;

    int qrow = w * 16 + lo;
    short8 qS0 = *(const short8*)&Qb[qrow * 64 + hi * 8];
    short8 qS1 = *(const short8*)&Qb[qrow * 64 + 32 + hi * 8];
    short8 qO0 = *(const short8*)&Ob[qrow * 64 + hi * 8];
    short8 qO1 = *(const short8*)&Ob[qrow * 64 + 32 + hi * 8];

    int jtd = it * 2 + (w >> 2);

    gload16(kS, &Kbuf[0][kd]);
    gload16(kS + 512, &Kbuf[0][kd + 512]);
    gload16(vS, &Vbuf[0][vd]);
    gload16(vS + 64, &Vbuf[0][vd + 4096]);
    __syncthreads();

    f32x4 oS[4] = {}, oO[4] = {};
    float mS[4], lS[4], mO[4], lO[4];
    #pragma unroll
    for (int r = 0; r < 4; ++r) { mS[r] = -1e30f; lS[r] = 0.f; mO[r] = -1e30f; lO[r] = 0.f; }

    for (int jt = 0; jt < 8; ++jt) {
        int j0 = jt * 128;
        int c = jt & 1;

        u16 a_[32];
        #pragma unroll
        for (int sub = 0; sub < 2; ++sub)
            #pragma unroll
            for (int jf = 0; jf < 4; ++jf)
                #pragma unroll
                for (int r = 0; r < 4; ++r)
                    a_[sub * 16 + jf * 4 + r] = AbL[(size_t)(r << 10) + j0 + sub * 64 + jf * 16];

        if (jt < 7) {
            int jn = j0 + 128;
            gload16(kS + (size_t)jn * 64, &Kbuf[c ^ 1][kd]);
            gload16(kS + (size_t)(jn + 8) * 64, &Kbuf[c ^ 1][kd + 512]);
            gload16(vS + jn, &Vbuf[c ^ 1][vd]);
            gload16(vS + jn + 64, &Vbuf[c ^ 1][vd + 4096]);
        }

        #pragma unroll
        for (int sub = 0; sub < 2; ++sub) {
            const u16* Kc = &Kbuf[c][sub * 4096];
            const u16* Vc = &Vbuf[c][sub * 4096];
            const u16* al = &a_[sub * 16];

            // ===== std pass =====
            f32x4 s[4];
            #pragma unroll
            for (int jf = 0; jf < 4; ++jf) {
                short8 kf0 = *(const short8*)&Kc[SW(jf * 16 + lo, hi)];
                short8 kf1 = *(const short8*)&Kc[SW(jf * 16 + lo, 4 + hi)];
                f32x4 z = {};
                z = __builtin_amdgcn_mfma_f32_16x16x32_bf16(qS0, kf0, z, 0, 0, 0);
                z = __builtin_amdgcn_mfma_f32_16x16x32_bf16(qS1, kf1, z, 0, 0, 0);
                s[jf] = z;
            }
            {
                float mx4[4];
                #pragma unroll
                for (int r = 0; r < 4; ++r)
                    mx4[r] = fmaxf(fmaxf(s[0][r], s[1][r]), fmaxf(s[2][r], s[3][r]));
                float need = fmaxf(fmaxf(mx4[0] - mS[0], mx4[1] - mS[1]),
                                   fmaxf(mx4[2] - mS[2], mx4[3] - mS[3]));
                if (!__all(need <= 8.0f)) {
                    #pragma unroll
                    for (int r = 0; r < 4; ++r) {
                        float mx = mx4[r];
                        #pragma unroll
                        for (int msk = 8; msk >= 1; msk >>= 1) mx = fmaxf(mx, __shfl_xor(mx, msk));
                        float mn = fmaxf(mS[r], mx);
                        float scl = __builtin_amdgcn_exp2f(mS[r] - mn);
                        mS[r] = mn;
                        lS[r] *= scl;
                        #pragma unroll
                        for (int df = 0; df < 4; ++df) oS[df][r] *= scl;
                    }
                }
                #pragma unroll
                for (int r = 0; r < 4; ++r)
                    #pragma unroll
                    for (int jf = 0; jf < 4; ++jf) {
                        float p = __builtin_amdgcn_exp2f(s[jf][r] - mS[r]);
                        s[jf][r] = p;
                        lS[r] += p;
                    }
            }
            #pragma unroll
            for (int jf = 0; jf < 4; ++jf)
                #pragma unroll
                for (int r = 0; r < 4; r += 2) {
                    int p0 = hi * 4 + r, p1 = p0 + 1;
                    u32 pk;
                    asm("v_cvt_pk_bf16_f32 %0, %1, %2" : "=v"(pk) : "v"(s[jf][r]), "v"(s[jf][r + 1]));
                    Ps[w * 1024 + p0 * 64 + ((jf * 16 + lo) ^ ((p0 & 7) * 8))] = (u16)pk;
                    Ps[w * 1024 + p1 * 64 + ((jf * 16 + lo) ^ ((p1 & 7) * 8))] = (u16)(pk >> 16);
                }
            {
                short8 pa0 = *(const short8*)&Ps[w * 1024 + SW(lo, hi)];
                short8 pa1 = *(const short8*)&Ps[w * 1024 + SW(lo, 4 + hi)];
                #pragma unroll
                for (int df = 0; df < 4; ++df) {
                    short8 v0 = *(const short8*)&Vc[SW(df * 16 + lo, hi)];
                    short8 v1 = *(const short8*)&Vc[SW(df * 16 + lo, 4 + hi)];
                    oS[df] = __builtin_amdgcn_mfma_f32_16x16x32_bf16(pa0, v0, oS[df], 0, 0, 0);
                    oS[df] = __builtin_amdgcn_mfma_f32_16x16x32_bf16(pa1, v1, oS[df], 0, 0, 0);
                }
            }

            // ===== OR pass =====
            #pragma unroll
            for (int jf = 0; jf < 4; ++jf) {
                short8 kf0 = *(const short8*)&Kc[SW(jf * 16 + lo, hi)];
                short8 kf1 = *(const short8*)&Kc[SW(jf * 16 + lo, 4 + hi)];
                f32x4 z = {};
                z = __builtin_amdgcn_mfma_f32_16x16x32_bf16(qO0, kf0, z, 0, 0, 0);
                z = __builtin_amdgcn_mfma_f32_16x16x32_bf16(qO1, kf1, z, 0, 0, 0);
                s[jf] = z;
            }
            #pragma unroll
            for (int jf = 0; jf < 4; ++jf)
                #pragma unroll
                for (int r = 0; r < 4; ++r) {
                    __half hv = __builtin_bit_cast(__half, al[jf * 4 + r]);
                    s[jf][r] *= __half2float(hv);
                }
            if (jt * 2 + sub == jtd) {
                #pragma unroll
                for (int jf = 0; jf < 4; ++jf)
                    #pragma unroll
                    for (int r = 0; r < 4; ++r)
                        s[jf][r] = ((jf == (w & 3)) && (hi * 4 + r == lo)) ? 0.0f : s[jf][r];
            }
            {
                float mx4[4];
                #pragma unroll
                for (int r = 0; r < 4; ++r)
                    mx4[r] = fmaxf(fmaxf(s[0][r], s[1][r]), fmaxf(s[2][r], s[3][r]));
                float need = fmaxf(fmaxf(mx4[0] - mO[0], mx4[1] - mO[1]),
                                   fmaxf(mx4[2] - mO[2], mx4[3] - mO[3]));
                if (!__all(need <= 8.0f)) {
                    #pragma unroll
                    for (int r = 0; r < 4; ++r) {
                        float mx = mx4[r];
                        #pragma unroll
                        for (int msk = 8; msk >= 1; msk >>= 1) mx = fmaxf(mx, __shfl_xor(mx, msk));
                        float mn = fmaxf(mO[r], mx);
                        float scl = __builtin_amdgcn_exp2f(mO[r] - mn);
                        mO[r] = mn;
                        lO[r] *= scl;
                        #pragma unroll
                        for (int df = 0; df < 4; ++df) oO[df][r] *= scl;
                    }
                }
                #pragma unroll
                for (int r = 0; r < 4; ++r)
                    #pragma unroll
                    for (int jf = 0; jf < 4; ++jf) {
                        float p = __builtin_amdgcn_exp2f(s[jf][r] - mO[r]);
                        s[jf][r] = p;
                        lO[r] += p;
                    }
            }
            #pragma unroll
            for (int jf = 0; jf < 4; ++jf)
                #pragma unroll
                for (int r = 0; r < 4; r += 2) {
                    int p0 = hi * 4 + r, p1 = p0 + 1;
                    u32 pk;
                    asm("v_cvt_pk_bf16_f32 %0, %1, %2" : "=v"(pk) : "v"(s[jf][r]), "v"(s[jf][r + 1]));
                    Ps[w * 1024 + p0 * 64 + ((jf * 16 + lo) ^ ((p0 & 7) * 8))] = (u16)pk;
                    Ps[w * 1024 + p1 * 64 + ((jf * 16 + lo) ^ ((p1 & 7) * 8))] = (u16)(pk >> 16);
                }
            {
                short8 pa0 = *(const short8*)&Ps[w * 1024 + SW(lo, hi)];
                short8 pa1 = *(const short8*)&Ps[w * 1024 + SW(lo, 4 + hi)];
                #pragma unroll
                for (int df = 0; df < 4; ++df) {
                    short8 v0 = *(const short8*)&Vc[SW(df * 16 + lo, hi)];
                    short8 v1 = *(const short8*)&Vc[SW(df * 16 + lo, 4 + hi)];
                    oO[df] = __builtin_amdgcn_mfma_f32_16x16x32_bf16(pa0, v0, oO[df], 0, 0, 0);
                    oO[df] = __builtin_amdgcn_mfma_f32_16x16x32_bf16(pa1, v1, oO[df], 0, 0, 0);
                }
            }
        }

        __syncthreads();
    }

    #pragma unroll
    for (int r = 0; r < 4; ++r) {
        float a = lS[r], c2 = lO[r];
        #pragma unroll
        for (int msk = 8; msk >= 1; msk >>= 1) {
            a += __shfl_xor(a, msk);
            c2 += __shfl_xor(c2, msk);
        }
        lS[r] = 1.0f / a;
        lO[r] = 1.0f / c2;
    }
    size_t obase = ((size_t)b * 1024 + i0 + w * 16 + hi * 4) * 512 + h * 64 + lo;
    #pragma unroll
    for (int df = 0; df < 4; ++df)
        #pragma unroll
        for (int r = 0; r < 4; ++r) {
            outS[obase + (size_t)r * 512 + df * 16] = f2bf(oS[df][r] * lS[r]);
            outO[obase + (size_t)r * 512 + df * 16] = f2bf(oO[df][r] * lO[r]);
        }
}

extern "C" void kernel_launch(void* const* d_in, const int* in_sizes, int n_in,
                              void* d_out, int out_size, void* d_ws, size_t ws_size,
                              hipStream_t stream)
{
    const float* x     = (const float*)d_in[0];
    const float* orqy  = (const float*)d_in[1];
    const float* alpha = (const float*)d_in[2];
    const float* ln_w  = (const float*)d_in[3];
    const float* ln_b  = (const float*)d_in[4];
    const float* w_qkv = (const float*)d_in[5];
    const float* w_orq = (const float*)d_in[6];
    const float* w_out = (const float*)d_in[7];
    float* outp = (float*)d_out;

    char* base = (char*)d_ws;
    size_t off = 0;
    auto alloc = [&](size_t bytes) -> char* {
        char* r = base + off;
        off += (bytes + 255) & ~(size_t)255;
        return r;
    };
    const size_t RC = 8192ull * 512 * 2; // one [8192,512] bf16 buffer
    u16* xn       = (u16*)alloc(RC);
    u16* orqn     = (u16*)alloc(RC);
    u16* qb       = (u16*)alloc(RC);
    u16* kb       = (u16*)alloc(RC);
    u16* vb       = (u16*)alloc(RC);   // stored transposed [bh][64][1024]
    u16* orqb     = (u16*)alloc(RC);
    u16* attout   = (u16*)alloc(RC);   // NOTE: attout/orattout contiguous
    u16* orattout = (u16*)alloc(RC);
    u16* wqkvT    = (u16*)alloc(1536ull * 512 * 2);
    u16* worqT    = (u16*)alloc(512ull * 512 * 2);
    u16* woutT    = (u16*)alloc(512ull * 512 * 2);
    u16* ascT     = (u16*)alloc(8ull * 1024 * 1024 * 2); // fp16 C_L2E*(1-alpha^T)

    // 1) all preprocessing in one launch
    prep_kernel<<<13568, 256, 0, stream>>>(x, orqy, alpha, ln_w, ln_b,
                                           w_qkv, w_orq, w_out,
                                           xn, orqn, wqkvT, worqT, woutT, ascT);
    // 2) qkv + orq projections (fully coalesced epilogues)
    gemm_kernel<<<dim3(16, 64), 256, 0, stream>>>(xn, wqkvT, orqn, worqT,
                                                  1536, 512, 3,
                                                  qb, kb, vb, orqb, nullptr);
    // 3) fused dual attention
    attn_fused_kernel<<<dim3(512), 512, 0, stream>>>(qb, orqb, kb, vb, ascT, attout, orattout);
    // 4) merged out-projection: A = [attout ; orattout] = 16384 rows (contiguous)
    gemm_kernel<<<dim3(4, 128), 256, 0, stream>>>(attout, woutT, nullptr, nullptr,
                                                  512, 512, 2,
                                                  nullptr, nullptr, nullptr, nullptr, outp);
}